// Round 2
// baseline (1096.578 us; speedup 1.0000x reference)
//
#include <hip/hip_runtime.h>
#include <math.h>

// ---------------------------------------------------------------------------
// DsDTW pipeline (round 14):
//  - dtw: split D(read)/R(write) into disjoint __restrict__ buffers
//    (D = old Db region, R = old Sb region; sc_k score output moves to the
//    dead Db region). Inner-loop D loads / R stores are inline-asm with a
//    hand-counted s_waitcnt vmcnt(8) per group: 8 loads stay in flight
//    across the 8 softmin steps, stores are fire-and-forget, vmcnt never
//    drains to 0 in the main loop.
//  - dtw: ONE 1024-thread block per sample (16 waves), LDS bot[] ring.
//  - QKV backfill: 768 blocks x 1024 threads, 4 tiles/block, LDS unioned.
// B=32, C_IN=12, T=4095, D=128, L=1024, GAMMA=5.
//
// ws (float offsets):
//   h     @ 0         [32,1024,128] f32 (dead after wout)
//   qkvb  @ 4194304   u16 slots: qb / kb / t0b / vt (4x 4,194,304 u16)
//   t0    @ 16777216  f32 (ff2 out, ln2 in-place)
//   t1    @ 20971520  f32 (wout out, ln1 in-place, ff2 residual)
//   t1b   @ 25165824  u16 (ln1 bf16; overlaps dead hbf)
//   t2b   @ 27262976  u16 (ff1 bf16)
//   mnmx  @ 27297792  (dead after sc)
//   norms @ 29360128  f32 (D2 only) -> then woutb/wff1b/wff2b/wlinb u16
//   rsum  @ 29425664
//   Dmat  @ 29458496  u16 skewed D (dtw input) -> reused as P after dtw
//   Rmat  @ 46235712  u16 skewed R (dtw output, read by sc_k)
// ---------------------------------------------------------------------------

#define L_SEQ 1024
#define DM 128
#define INF_F __builtin_inff()

typedef short s16x8 __attribute__((ext_vector_type(8)));
typedef float f32x4 __attribute__((ext_vector_type(4)));
typedef unsigned short u16;

__device__ __forceinline__ float b2f(u16 u) {
    return __uint_as_float(((unsigned)u) << 16);
}
__device__ __forceinline__ u16 f2b(float f) {  // RNE
    unsigned u = __float_as_uint(f);
    return (u16)((u + 0x7FFFu + ((u >> 16) & 1u)) >> 16);
}
__device__ __forceinline__ u16 f2bt(float f) {  // truncate (cheap)
    return (u16)(__float_as_uint(f) >> 16);
}

__device__ __forceinline__ float shup1(float x) {
#if __has_builtin(__builtin_amdgcn_mov_dpp)
    return __int_as_float(
        __builtin_amdgcn_mov_dpp(__float_as_int(x), 0x138, 0xF, 0xF, true));
#else
    return __shfl_up(x, 1);
#endif
}

// ---------------- conv + pool + relu + mask + row norms --------------------
__global__ __launch_bounds__(128) void conv_k(
    const float* __restrict__ x, const float* __restrict__ w,
    const float* __restrict__ cb, const float* __restrict__ mask,
    float* __restrict__ h, u16* __restrict__ hbf, float* __restrict__ norms)
{
    int b = blockIdx.x;
    int l0 = blockIdx.y * 8;
    int d = threadIdx.x;
    __shared__ float xs[12][36];
    __shared__ float red2[8][2];
    for (int v = d; v < 12 * 35; v += 128) {
        int c = v / 35, off = v % 35;
        int gi = 4 * l0 - 2 + off;
        xs[c][off] = (gi >= 0 && gi < 4095) ? x[((long)b * 12 + c) * 4095 + gi] : 0.f;
    }
    __syncthreads();
    float s[8];
#pragma unroll
    for (int l = 0; l < 8; ++l) s[l] = 0.f;
    for (int c = 0; c < 12; ++c) {
        const float* wp = w + (d * 12 + c) * 4;
        float w0 = wp[0], w1 = wp[1], w2 = wp[2], w3 = wp[3];
        float e0 = w0, e1 = w0 + w1, e2 = w0 + w1 + w2, e3 = w0 + w1 + w2 + w3;
        float e4 = w1 + w2 + w3, e5 = w2 + w3, e6 = w3;
#pragma unroll
        for (int l = 0; l < 8; ++l) {
            int ba = 4 * l;
            s[l] += xs[c][ba] * e0 + xs[c][ba + 1] * e1 + xs[c][ba + 2] * e2 +
                    xs[c][ba + 3] * e3 + xs[c][ba + 4] * e4 + xs[c][ba + 5] * e5 +
                    xs[c][ba + 6] * e6;
        }
    }
    float cbd = cb[d];
#pragma unroll
    for (int l = 0; l < 8; ++l) {
        int gl = l0 + l;
        float val = fmaxf(cbd + 0.25f * s[l], 0.f) * mask[b * L_SEQ + gl];
        long idx = ((long)(b * L_SEQ + gl)) * DM + d;
        h[idx] = val;
        hbf[idx] = f2b(val);
        float vsq = val * val;
#pragma unroll
        for (int m = 1; m < 64; m <<= 1) vsq += __shfl_xor(vsq, m);
        if ((d & 63) == 0) red2[l][d >> 6] = vsq;
    }
    __syncthreads();
    if (d < 8) norms[(long)b * L_SEQ + l0 + d] = red2[d][0] + red2[d][1];
}

// ----------------------- weight fp32 -> bf16 convert -----------------------
__global__ __launch_bounds__(256) void wcvt_k(
    const float* __restrict__ w1, const float* __restrict__ w2,
    const float* __restrict__ w3, const float* __restrict__ w4,
    u16* __restrict__ o)
{
    int i = blockIdx.x * 256 + threadIdx.x;   // grid 200 -> 51200
    float v;
    if (i < 16384) v = w1[i];
    else if (i < 32768) v = w2[i - 16384];
    else if (i < 49152) v = w3[i - 32768];
    else v = w4[i - 49152];
    o[i] = f2b(v);
}

// --------------------------- MFMA bf16 GEMMs -------------------------------
enum MGMode { G_D2, G_AV };

template <int MODE>
__global__ __launch_bounds__(256) void mgemm_k(
    const u16* __restrict__ A0, const u16* __restrict__ B0, void* __restrict__ C0,
    const float* __restrict__ e0, const float* __restrict__ rsum)
{
    constexpr int LDK = (MODE == G_AV) ? 1024 : 128;
    constexpr int KK = LDK / 32;
    const int z = blockIdx.z;
    const u16* A = A0 + (MODE == G_D2 ? 0L : (long)z * 1048576L);
    const u16* B = B0 + (long)z * 131072L;
    const int tid = threadIdx.x, wv = tid >> 6, lane = tid & 63;
    const int m0 = blockIdx.x * 64, n0 = blockIdx.y * 64;
    const int co = lane & 15;
    const int q8 = (lane >> 4) << 3;
    const int mrow = m0 + 16 * wv + co;

    f32x4 acc[4];
#pragma unroll
    for (int tn = 0; tn < 4; ++tn) acc[tn] = 0.f;

    for (int kk = 0; kk < KK; ++kk) {
        const int k0 = kk * 32 + q8;
        const s16x8 a = *reinterpret_cast<const s16x8*>(A + (long)mrow * LDK + k0);
#pragma unroll
        for (int tn = 0; tn < 4; ++tn) {
            const s16x8 b = *reinterpret_cast<const s16x8*>(
                B + (long)(n0 + 16 * tn + co) * LDK + k0);
            acc[tn] = __builtin_amdgcn_mfma_f32_16x16x32_bf16(a, b, acc[tn], 0, 0, 0);
        }
    }

    const int li0 = 16 * wv + ((lane >> 4) << 2);

    if (MODE == G_D2) {
        __shared__ float Cs[64][66];
        float ni[4];
#pragma unroll
        for (int r = 0; r < 4; ++r) ni[r] = e0[m0 + li0 + r];
#pragma unroll
        for (int tn = 0; tn < 4; ++tn) {
            float nj = e0[(long)z * L_SEQ + n0 + 16 * tn + co];
#pragma unroll
            for (int r = 0; r < 4; ++r)
                Cs[li0 + r][16 * tn + co] = ni[r] + nj - 2.f * acc[tn][r];
        }
        __syncthreads();
        u16* Cu = (u16*)C0 + (long)z * 1048576L;
        for (int q = 0; q < 32; ++q) {
            int dd = wv * 32 + q;
            if (dd < 127) {
                int d = m0 + n0 + dd;
                int ilo = max(m0, d - n0 - 63);
                int ihi = min(m0 + 63, d - n0);
                int i = ilo + lane;
                if (i <= ihi)
                    Cu[(long)(((d & 1023) << 10) + i)] = f2b(Cs[i - m0][d - n0 - i]);
            }
        }
        return;
    }
    // G_AV: t0b (bf16) = (P . V) * rsuminv[row]
    {
        u16* Cb = (u16*)C0 + (long)z * 131072L;
        float rsv[4];
#pragma unroll
        for (int r = 0; r < 4; ++r) rsv[r] = rsum[(long)z * L_SEQ + m0 + li0 + r];
#pragma unroll
        for (int tn = 0; tn < 4; ++tn)
#pragma unroll
            for (int r = 0; r < 4; ++r)
                Cb[(long)(m0 + li0 + r) * 128 + n0 + 16 * tn + co] =
                    f2b(acc[tn][r] * rsv[r]);
    }
}

// ---------------------- SC (MFMA scores), one launch -----------------------
// reads R from Rm (dtw output), writes scores into So (the dead D region)
__global__ __launch_bounds__(256) void sc_k(
    const u16* __restrict__ qb, const u16* __restrict__ kb, u16* __restrict__ So,
    const float* __restrict__ mnmx, const float* __restrict__ mask,
    const u16* __restrict__ Rm)
{
    const int s = blockIdx.x;
    const int tid = threadIdx.x;
    __shared__ float Rs[64][66];

    const int z = s >> 8;
    const int m0 = (s & 15) * 64, n0 = ((s >> 4) & 15) * 64;
    const u16* A = qb + (long)z * 131072L;
    const u16* B = kb + (long)z * 131072L;
    const int wv = tid >> 6, lane = tid & 63;
    const int co = lane & 15;
    const int q8 = (lane >> 4) << 3;
    const int mrow = m0 + 16 * wv + co;

    f32x4 acc[4];
#pragma unroll
    for (int tn = 0; tn < 4; ++tn) acc[tn] = 0.f;
    for (int kk = 0; kk < 4; ++kk) {
        const int k0 = kk * 32 + q8;
        const s16x8 a = *reinterpret_cast<const s16x8*>(A + (long)mrow * 128 + k0);
#pragma unroll
        for (int tn = 0; tn < 4; ++tn) {
            const s16x8 b = *reinterpret_cast<const s16x8*>(
                B + (long)(n0 + 16 * tn + co) * 128 + k0);
            acc[tn] = __builtin_amdgcn_mfma_f32_16x16x32_bf16(a, b, acc[tn], 0, 0, 0);
        }
    }
    const int li0 = 16 * wv + ((lane >> 4) << 2);
    const u16* Rz = Rm + (long)z * 1048576L;
    for (int q = 0; q < 32; ++q) {
        int dd = wv * 32 + q;
        if (dd < 127) {
            int d = m0 + n0 + dd;
            int ilo = max(m0, d - n0 - 63);
            int ihi = min(m0 + 63, d - n0);
            int i = ilo + lane;
            if (i <= ihi)
                Rs[i - m0][d - n0 - i] = b2f(Rz[(long)(((d & 1023) << 10) + i)]);
        }
    }
    __syncthreads();
    float mn = fminf(mnmx[4 * z + 0], mnmx[4 * z + 2]);
    float mx = fmaxf(mnmx[4 * z + 1], mnmx[4 * z + 3]);
    float inv = 1.f / (mx - mn);
    u16* Cu = So + (long)z * 1048576L;
#pragma unroll
    for (int tn = 0; tn < 4; ++tn) {
        int gj = n0 + 16 * tn + co;
        float kp = (mask[(long)z * L_SEQ + gj] > 0.f) ? 0.f : -INF_F;
#pragma unroll
        for (int r = 0; r < 4; ++r) {
            float val = acc[tn][r] * 0.08838834764831845f +
                        (Rs[li0 + r][16 * tn + co] - mn) * inv + 1.f + kp;
            Cu[(long)(m0 + li0 + r) * 1024 + gj] = f2b(val);
        }
    }
}

// ----------------- MFMA weight GEMMs (M=32768, K=128) ----------------------
enum WMode { W2_WOUT, W2_FF1, W2_FF2, W2_LIN };

template <int MODE, int NT>
__global__ __launch_bounds__(256) void wgemm_k(
    const u16* __restrict__ A, const u16* __restrict__ Bw, void* __restrict__ Cv,
    const float* __restrict__ bias, const float* __restrict__ e1)
{
    const int tid = threadIdx.x, wv = tid >> 6, lane = tid & 63;
    const int m0 = blockIdx.x * 64, n0 = blockIdx.y * 64;
    const int co = lane & 15;
    const int q8 = (lane >> 4) << 3;
    const int mrow = m0 + 16 * wv + co;

    f32x4 acc[NT];
#pragma unroll
    for (int tn = 0; tn < NT; ++tn) acc[tn] = 0.f;
    for (int kk = 0; kk < 4; ++kk) {
        const int k0 = kk * 32 + q8;
        const s16x8 a = *reinterpret_cast<const s16x8*>(A + (long)mrow * 128 + k0);
#pragma unroll
        for (int tn = 0; tn < NT; ++tn) {
            const s16x8 b = *reinterpret_cast<const s16x8*>(
                Bw + (long)(n0 + 16 * tn + co) * 128 + k0);
            acc[tn] = __builtin_amdgcn_mfma_f32_16x16x32_bf16(a, b, acc[tn], 0, 0, 0);
        }
    }
    const int li0 = 16 * wv + ((lane >> 4) << 2);
#pragma unroll
    for (int tn = 0; tn < NT; ++tn) {
        int gj = n0 + 16 * tn + co;
#pragma unroll
        for (int r = 0; r < 4; ++r) {
            int gi = m0 + li0 + r;
            long idx = (long)gi * 128 + gj;
            float v = acc[tn][r];
            if (MODE == W2_WOUT) {
                ((float*)Cv)[idx] = v + bias[gj] + e1[idx];
            } else if (MODE == W2_FF1) {
                ((u16*)Cv)[idx] = f2b(fmaxf(v + bias[gj], 0.f));
            } else if (MODE == W2_FF2) {
                ((float*)Cv)[idx] = v + bias[gj] + e1[idx];
            } else if (MODE == W2_LIN) {
                ((float*)Cv)[(long)gi * 16 + gj] = v * e1[gi];
            }
        }
    }
}

// ------------------------------- soft-DTW ----------------------------------
__device__ __forceinline__ float softmin3(float d, float rl, float ru, float rul)
{
    float mn = fminf(rul, fminf(ru, rl));
    float md = fmaxf(fminf(rul, ru), fminf(fmaxf(rul, ru), rl));
    float mx = fmaxf(rul, fmaxf(ru, rl));
    float s = 1.f + __expf((mn - md) * 0.2f) + __expf((mn - mx) * 0.2f);
    return d + mn - 5.0f * __logf(s);
}

// D loads / R stores via inline asm: 8 loads in flight across the 8-step
// chain, counted s_waitcnt vmcnt(8) at group end (leaves this group's 8
// stores outstanding), never drains to 0 in the main loop.
template <bool EDGE>
__device__ __forceinline__ void dtw_chunk1(
    const u16* __restrict__ Dz, u16* __restrict__ Rz,
    const float* __restrict__ botp, float* __restrict__ botw,
    int W, int lane, bool lane0, int rowbase, int row, int T0,
    float& cur, float& upc, float& upp, float& vmin, float& vmax,
    float (&dbuf)[8], float (&bb)[9], unsigned (&dn)[8])
{
    u16* sp = Rz + (((T0 & 1023) << 10) + row);
    const bool w0 = (W == 0);
    const bool wstore = (W < 15);
    for (int g = 0; g < 4; ++g) {
        const int tg = T0 + (g << 3);
        // issue next group's 8 D loads (stay in flight across the steps)
#pragma unroll
        for (int s = 0; s < 8; ++s) {
            const u16* ap = Dz + ((((tg + 8 + s) & 1023) << 10) + row);
            asm volatile("global_load_ushort %0, %1, off"
                         : "=v"(dn[s]) : "v"(ap));
        }
        float bn[9];
        if (W > 0 && g < 3) {
            const int jn = tg + 7 - rowbase;
#pragma unroll
            for (int q = 0; q < 9; ++q) bn[q] = botp[(jn + q) & 511];
        }
#pragma unroll
        for (int s = 0; s < 8; ++s) {
            const int t = tg + s;
            const int j = t - row;
            float ru = lane0 ? (w0 ? INF_F : bb[s + 1]) : upc;
            float rul = upp;
            if (EDGE) {
                rul = lane0 ? (w0 ? ((j == 0) ? 0.f : INF_F)
                                  : ((j < 1) ? INF_F : upp))
                            : upp;
            } else {
                rul = (lane0 && w0) ? INF_F : rul;
            }
            float n = softmin3(dbuf[s], cur, ru, rul);
            if (EDGE) {
                bool v = ((unsigned)j < 1024u);
                n = v ? n : INF_F;
                vmin = fminf(vmin, n);
                vmax = v ? fmaxf(vmax, n) : vmax;
                if (v) {
                    unsigned bits = __float_as_uint(n) >> 16;
                    asm volatile("global_store_short %0, %1, off"
                                 :: "v"(sp), "v"(bits));
                }
                if (lane == 63 && v && wstore) botw[j & 511] = n;
            } else {
                vmin = fminf(vmin, n);
                vmax = fmaxf(vmax, n);
                unsigned bits = __float_as_uint(n) >> 16;
                asm volatile("global_store_short %0, %1, off"
                             :: "v"(sp), "v"(bits));
                if (lane == 63 && wstore) botw[j & 511] = n;
            }
            upp = ru;
            cur = n;
            upc = shup1(n);
            sp += 1024;
        }
        // retire the 8 loads (8 newest ops = this group's stores may remain)
        asm volatile("s_waitcnt vmcnt(8)");
        __builtin_amdgcn_sched_barrier(0);
#pragma unroll
        for (int s = 0; s < 8; ++s) dbuf[s] = __uint_as_float(dn[s] << 16);
        if (W > 0 && g < 3) {
#pragma unroll
            for (int q = 0; q < 9; ++q) bb[q] = bn[q];
        }
    }
}

// dtw (blocks 0..31: 1 per sample, 16 waves) + QKV backfill (blocks 32..799)
__global__ __launch_bounds__(1024, 4) void dtw_qkv_k(
    const u16* __restrict__ Dm, u16* __restrict__ Rm, float* __restrict__ minmax,
    const float* __restrict__ h, const float* __restrict__ w_in,
    const float* __restrict__ b_in, u16* __restrict__ qb, u16* __restrict__ vt)
{
    // unioned LDS: QKV As(16640)+Bs(16640) | QKV Tt(33280) | dtw bot(30720)/red(8192)
    __shared__ __align__(16) char smem[33280];

    if (blockIdx.x >= 32) {
        // ---- QKV backfill: four 64x64 tiles per 1024-thread block ----
        float (*As)[16][65] = reinterpret_cast<float (*)[16][65]>(smem);
        float (*Bs)[16][65] = reinterpret_cast<float (*)[16][65]>(smem + 16640);
        const int quarter = threadIdx.x >> 8;
        const int tid = threadIdx.x & 255;
        const int t = ((blockIdx.x - 32) << 2) + quarter;   // 0..3071
        const int m0 = (t & 511) << 6;
        const int n0 = (t >> 9) << 6;                       // block-uniform
        int tx = tid & 15, ty = tid >> 4;
        float acc[4][4] = {};
        int am = tid >> 2;
        int ak = (tid & 3) << 2;
        for (int kk = 0; kk < 128; kk += 16) {
            {
                const float4 av = *reinterpret_cast<const float4*>(
                    h + (long)(m0 + am) * 128 + kk + ak);
                As[quarter][ak + 0][am] = av.x;
                As[quarter][ak + 1][am] = av.y;
                As[quarter][ak + 2][am] = av.z;
                As[quarter][ak + 3][am] = av.w;
            }
            {
                const float4 bv = *reinterpret_cast<const float4*>(
                    w_in + (long)(n0 + am) * 128 + kk + ak);
                Bs[quarter][ak + 0][am] = bv.x;
                Bs[quarter][ak + 1][am] = bv.y;
                Bs[quarter][ak + 2][am] = bv.z;
                Bs[quarter][ak + 3][am] = bv.w;
            }
            __syncthreads();
#pragma unroll
            for (int kc = 0; kc < 16; ++kc) {
                float a0 = As[quarter][kc][ty * 4 + 0], a1 = As[quarter][kc][ty * 4 + 1];
                float a2 = As[quarter][kc][ty * 4 + 2], a3 = As[quarter][kc][ty * 4 + 3];
                float b0 = Bs[quarter][kc][tx * 4 + 0], b1 = Bs[quarter][kc][tx * 4 + 1];
                float b2 = Bs[quarter][kc][tx * 4 + 2], b3 = Bs[quarter][kc][tx * 4 + 3];
                acc[0][0] += a0 * b0; acc[0][1] += a0 * b1; acc[0][2] += a0 * b2; acc[0][3] += a0 * b3;
                acc[1][0] += a1 * b0; acc[1][1] += a1 * b1; acc[1][2] += a1 * b2; acc[1][3] += a1 * b3;
                acc[2][0] += a2 * b0; acc[2][1] += a2 * b1; acc[2][2] += a2 * b2; acc[2][3] += a2 * b3;
                acc[3][0] += a3 * b0; acc[3][1] += a3 * b1; acc[3][2] += a3 * b2; acc[3][3] += a3 * b3;
            }
            __syncthreads();
        }
        if (n0 >= 256) {
            // v-tile: write TRANSPOSED into vt [d,1024] via LDS (Tt aliases As/Bs;
            // safe: k-loop ends with a block-wide barrier)
            u16 (*Tt)[64][65] = reinterpret_cast<u16 (*)[64][65]>(smem);
#pragma unroll
            for (int i = 0; i < 4; ++i)
#pragma unroll
                for (int j = 0; j < 4; ++j)
                    Tt[quarter][tx * 4 + j][ty * 4 + i] =
                        f2b(acc[i][j] + b_in[n0 + tx * 4 + j]);
            __syncthreads();
            const int z = m0 >> 10;
            const int lbase = m0 & 1023;
            const int dbase = n0 - 256;
            u16* dst = vt + (long)z * 131072L;
#pragma unroll
            for (int i = 0; i < 16; ++i) {
                int idx = tid + 256 * i;
                int dj = idx >> 6, li = idx & 63;
                dst[(long)(dbase + dj) * 1024 + lbase + li] = Tt[quarter][dj][li];
            }
            return;
        }
        u16* Cu = qb + ((long)(n0 >> 7)) * 4194304L;
        int cb = (n0 & 127) + tx * 4;
#pragma unroll
        for (int i = 0; i < 4; ++i) {
            int gi = m0 + ty * 4 + i;
            ushort4 sv;
            u16* svp = &sv.x;
#pragma unroll
            for (int j = 0; j < 4; ++j)
                svp[j] = f2b(acc[i][j] + b_in[n0 + tx * 4 + j]);
            *reinterpret_cast<ushort4*>(Cu + (long)gi * 128 + cb) = sv;
        }
        return;
    }

    // ------------------------------- dtw ---------------------------------
    float (*bot)[512] = reinterpret_cast<float (*)[512]>(smem);
    const int z = blockIdx.x;
    const u16* Dz = Dm + (long)z * 1048576L;
    u16* Rz = Rm + (long)z * 1048576L;
    const int tid = threadIdx.x;
    const int W = tid >> 6;           // 0..15, 64 rows each
    const int lane = tid & 63;
    const bool lane0 = (lane == 0);
    const int rowbase = 64 * W;
    const int row = rowbase + lane;

    float* botw = (W < 15) ? bot[W] : bot[0];
    const float* botp = (W > 0) ? bot[W - 1] : bot[0];

    float cur = INF_F, upc = INF_F, upp = INF_F;
    float vmin = INF_F, vmax = -INF_F;
    float dbuf[8];
    float bb[9];
    unsigned dn[8];
#pragma unroll
    for (int q = 0; q < 9; ++q) bb[q] = 0.f;
#pragma unroll
    for (int q = 0; q < 8; ++q) dn[q] = 0;

    const int fc = 2 * W;
    for (int e = 0; e < 79; ++e) {
        const int c = e - W;
        const int o = c - fc;
        if (o >= 0 && o <= 33) {
            const int T0 = c << 5;
            if (o == 0) {   // prime D queue (8 steps)
#pragma unroll
                for (int s = 0; s < 8; ++s)
                    dbuf[s] = b2f(Dz[((((T0 + s) & 1023) << 10) + row)]);
            }
            if (W > 0) {    // bot columns for the chunk's first group
                const int jb = T0 - rowbase - 1;
#pragma unroll
                for (int q = 0; q < 9; ++q) bb[q] = botp[(jb + q) & 511];
            }
            if (o < 2 || o >= 32)
                dtw_chunk1<true>(Dz, Rz, botp, botw, W, lane, lane0,
                                 rowbase, row, T0,
                                 cur, upc, upp, vmin, vmax, dbuf, bb, dn);
            else
                dtw_chunk1<false>(Dz, Rz, botp, botw, W, lane, lane0,
                                  rowbase, row, T0,
                                  cur, upc, upp, vmin, vmax, dbuf, bb, dn);
        }
        __syncthreads();
    }

    // min/max reduction over 1024 threads (red aliases dead bot ring)
    float* rmn = reinterpret_cast<float*>(smem);
    float* rmx = rmn + 1024;
    rmn[tid] = vmin;
    rmx[tid] = vmax;
    __syncthreads();
    for (int s2 = 512; s2 > 0; s2 >>= 1) {
        if (tid < s2) {
            rmn[tid] = fminf(rmn[tid], rmn[tid + s2]);
            rmx[tid] = fmaxf(rmx[tid], rmx[tid + s2]);
        }
        __syncthreads();
    }
    if (tid == 0) {
        minmax[z * 4 + 0] = rmn[0];
        minmax[z * 4 + 1] = rmx[0];
        minmax[z * 4 + 2] = rmn[0];   // duplicate so sc_k stays unchanged
        minmax[z * 4 + 3] = rmx[0];
    }
}

// ---------- softmax row stats + in-place P = exp(s-max), wave/row ----------
__global__ __launch_bounds__(256) void smax_k(u16* __restrict__ S,
                                              float* __restrict__ rsuminv)
{
    long row = (long)blockIdx.x * 4 + (threadIdx.x >> 6);
    int lane = threadIdx.x & 63;
    u16* p = S + row * L_SEQ + lane * 16;
    ushort4 v[4];
#pragma unroll
    for (int q = 0; q < 4; ++q) v[q] = reinterpret_cast<ushort4*>(p)[q];
    float f[16];
#pragma unroll
    for (int q = 0; q < 4; ++q) {
        f[4 * q + 0] = b2f(v[q].x);
        f[4 * q + 1] = b2f(v[q].y);
        f[4 * q + 2] = b2f(v[q].z);
        f[4 * q + 3] = b2f(v[q].w);
    }
    float m = f[0];
#pragma unroll
    for (int i = 1; i < 16; ++i) m = fmaxf(m, f[i]);
#pragma unroll
    for (int d2 = 1; d2 < 64; d2 <<= 1) m = fmaxf(m, __shfl_xor(m, d2));
    float s = 0.f;
#pragma unroll
    for (int i = 0; i < 16; ++i) {
        f[i] = __expf(f[i] - m);
        s += f[i];
    }
#pragma unroll
    for (int q = 0; q < 4; ++q) {
        ushort4 pv;
        pv.x = f2b(f[4 * q + 0]);
        pv.y = f2b(f[4 * q + 1]);
        pv.z = f2b(f[4 * q + 2]);
        pv.w = f2b(f[4 * q + 3]);
        reinterpret_cast<ushort4*>(p)[q] = pv;
    }
#pragma unroll
    for (int d2 = 1; d2 < 64; d2 <<= 1) s += __shfl_xor(s, d2);
    if (lane == 0) rsuminv[row] = 1.f / s;
}

// ------------------ layernorm (wave/row), fp32 + bf16 out ------------------
__global__ __launch_bounds__(256) void ln_k(float* __restrict__ X,
                                            u16* __restrict__ Xb,
                                            const float* __restrict__ g,
                                            const float* __restrict__ b)
{
    long row = (long)blockIdx.x * 4 + (threadIdx.x >> 6);
    int lane = threadIdx.x & 63;
    float2 x = *reinterpret_cast<float2*>(X + row * DM + lane * 2);
    float s = x.x + x.y;
    float q = x.x * x.x + x.y * x.y;
#pragma unroll
    for (int m = 1; m < 64; m <<= 1) {
        s += __shfl_xor(s, m);
        q += __shfl_xor(q, m);
    }
    float mean = s * (1.f / 128.f);
    float var = q * (1.f / 128.f) - mean * mean;
    float rstd = rsqrtf(var + 1e-5f);
    float2 o;
    o.x = (x.x - mean) * rstd * g[lane * 2 + 0] + b[lane * 2 + 0];
    o.y = (x.y - mean) * rstd * g[lane * 2 + 1] + b[lane * 2 + 1];
    *reinterpret_cast<float2*>(X + row * DM + lane * 2) = o;
    ushort2 ob;
    ob.x = f2b(o.x);
    ob.y = f2b(o.y);
    *reinterpret_cast<ushort2*>(Xb + row * DM + lane * 2) = ob;
}

// -------------------------------- lengths ----------------------------------
__global__ __launch_bounds__(256) void len_k(const float* __restrict__ mask,
                                             float* __restrict__ out)
{
    int b = blockIdx.x;
    int t = threadIdx.x;
    const float4 v = reinterpret_cast<const float4*>(mask + b * L_SEQ)[t];
    __shared__ float red[256];
    red[t] = v.x + v.y + v.z + v.w;
    __syncthreads();
    for (int s = 128; s > 0; s >>= 1) {
        if (t < s) red[t] += red[t + s];
        __syncthreads();
    }
    if (t == 0) out[b] = red[0];
}

// ------------------------------- launcher ----------------------------------
extern "C" void kernel_launch(void* const* d_in, const int* in_sizes, int n_in,
                              void* d_out, int out_size, void* d_ws, size_t ws_size,
                              hipStream_t stream)
{
    const float* x      = (const float*)d_in[0];
    const float* mask   = (const float*)d_in[1];
    const float* conv_w = (const float*)d_in[2];
    const float* conv_b = (const float*)d_in[3];
    const float* w_in   = (const float*)d_in[4];
    const float* b_in   = (const float*)d_in[5];
    const float* w_out  = (const float*)d_in[6];
    const float* b_out  = (const float*)d_in[7];
    const float* w_ff1  = (const float*)d_in[8];
    const float* b_ff1  = (const float*)d_in[9];
    const float* w_ff2  = (const float*)d_in[10];
    const float* b_ff2  = (const float*)d_in[11];
    const float* ln1_g  = (const float*)d_in[12];
    const float* ln1_b  = (const float*)d_in[13];
    const float* ln2_g  = (const float*)d_in[14];
    const float* ln2_b  = (const float*)d_in[15];
    const float* w_lin  = (const float*)d_in[16];
    float* out = (float*)d_out;

    float* ws    = (float*)d_ws;
    float* h     = ws;
    u16*   qb    = (u16*)(ws + 4194304L);
    u16*   kb    = qb + 4194304L;
    u16*   t0b   = qb + 8388608L;
    u16*   vt    = qb + 12582912L;
    float* t0    = ws + 16777216L;
    float* t1    = ws + 20971520L;
    u16*   t1b   = (u16*)(ws + 25165824L);    // overlaps hbf (dead after D2)
    u16*   hbf   = (u16*)(ws + 25165824L);
    u16*   t2b   = t1b + 4194304L;            // overlaps dead mnmx region
    float* mnmx  = ws + 27297792L;
    float* norms = ws + 29360128L;
    u16*   woutb = (u16*)norms;               // weights after D2 consumed norms
    u16*   wff1b = woutb + 16384;
    u16*   wff2b = woutb + 32768;
    u16*   wlinb = woutb + 49152;
    float* rsum  = ws + 29425664L;
    u16*   Dmat  = (u16*)(ws + 29458496L);    // D (dtw input), then P after sc
    u16*   Rmat  = (u16*)(ws + 46235712L);    // R (dtw output, sc input)
    u16*   Pmat  = Dmat;                      // scores/P (D dead after dtw)

    conv_k<<<dim3(32, 128), 128, 0, stream>>>(x, conv_w, conv_b, mask, h, hbf, norms);
    mgemm_k<G_D2><<<dim3(16, 16, 32), 256, 0, stream>>>(
        hbf, hbf, Dmat, norms, nullptr);
    wcvt_k<<<200, 256, 0, stream>>>(w_out, w_ff1, w_ff2, w_lin, woutb);
    // dtw (32 blocks, 1/sample, 16 waves) + qkv backfill (768 blocks x 4 tiles)
    dtw_qkv_k<<<800, 1024, 0, stream>>>(Dmat, Rmat, mnmx, h, w_in, b_in, qb, vt);
    sc_k<<<8192, 256, 0, stream>>>(qb, kb, Pmat, mnmx, mask, Rmat);
    smax_k<<<8192, 256, 0, stream>>>(Pmat, rsum);
    mgemm_k<G_AV><<<dim3(16, 2, 32), 256, 0, stream>>>(
        Pmat, vt, t0b, nullptr, rsum);
    wgemm_k<W2_WOUT, 4><<<dim3(512, 2), 256, 0, stream>>>(
        t0b, woutb, t1, b_out, h);
    ln_k<<<8192, 256, 0, stream>>>(t1, t1b, ln1_g, ln1_b);
    wgemm_k<W2_FF1, 4><<<dim3(512, 2), 256, 0, stream>>>(
        t1b, wff1b, t2b, b_ff1, nullptr);
    wgemm_k<W2_FF2, 4><<<dim3(512, 2), 256, 0, stream>>>(
        t2b, wff2b, t0, b_ff2, t1);
    ln_k<<<8192, 256, 0, stream>>>(t0, t0b, ln2_g, ln2_b);
    wgemm_k<W2_LIN, 1><<<dim3(512, 1), 256, 0, stream>>>(
        t0b, wlinb, out, nullptr, mask);
    len_k<<<32, 256, 0, stream>>>(mask, out + 32768L * 16);
}

// Round 3
// 943.032 us; speedup vs baseline: 1.1628x; 1.1628x over previous
//
#include <hip/hip_runtime.h>
#include <math.h>

// ---------------------------------------------------------------------------
// DsDTW pipeline (round 15):
//  - dtw softmin in BASE-2 scaled domain: R'' = R * (log2e/gamma). The
//    min-max normalization is scale-invariant, so no unscale needed.
//    softmin step = min3/med3/max3 + 2x v_exp_f32 + v_log_f32, no muls.
//    Scale constant folded into conv_k norms and mgemm D2 epilogue.
//  - min/max tracking removed from the dtw hot loop; a post-pass mm_k
//    scans Rmat (every slot holds exactly one valid R value).
//  - dtw: ONE 1024-thread block per sample (16 waves), LDS bot[] ring,
//    asm-pipelined D loads / R stores with counted vmcnt(8).
//  - QKV backfill: 768 blocks x 1024 threads, 4 tiles/block, LDS unioned.
// B=32, C_IN=12, T=4095, D=128, L=1024, GAMMA=5.
//
// ws (float offsets):
//   h     @ 0         [32,1024,128] f32 (dead after wout)
//   qkvb  @ 4194304   u16 slots: qb / kb / t0b / vt (4x 4,194,304 u16)
//   t0    @ 16777216  f32 (ff2 out, ln2 in-place)
//   t1    @ 20971520  f32 (wout out, ln1 in-place, ff2 residual)
//   t1b   @ 25165824  u16 (ln1 bf16; overlaps dead hbf)
//   t2b   @ 27262976  u16 (ff1 bf16)
//   mnmx  @ 27297792  (dead after sc)
//   norms @ 29360128  f32 (D2 only) -> then woutb/wff1b/wff2b/wlinb u16
//   rsum  @ 29425664
//   Dmat  @ 29458496  u16 skewed D (dtw input) -> reused as P after dtw
//   Rmat  @ 46235712  u16 skewed R (dtw output, read by mm_k + sc_k)
// ---------------------------------------------------------------------------

#define L_SEQ 1024
#define DM 128
#define INF_F __builtin_inff()

// log2(e)/gamma and 2*log2(e)/gamma
#define K_SCALE 0.28853900817779268f
#define K2_SCALE 0.57707801635558536f

typedef short s16x8 __attribute__((ext_vector_type(8)));
typedef float f32x4 __attribute__((ext_vector_type(4)));
typedef unsigned short u16;

__device__ __forceinline__ float b2f(u16 u) {
    return __uint_as_float(((unsigned)u) << 16);
}
__device__ __forceinline__ u16 f2b(float f) {  // RNE
    unsigned u = __float_as_uint(f);
    return (u16)((u + 0x7FFFu + ((u >> 16) & 1u)) >> 16);
}
__device__ __forceinline__ u16 f2bt(float f) {  // truncate (cheap)
    return (u16)(__float_as_uint(f) >> 16);
}

__device__ __forceinline__ float fexp2(float x) {
    float r;
    asm("v_exp_f32 %0, %1" : "=v"(r) : "v"(x));
    return r;
}
__device__ __forceinline__ float flog2(float x) {
    float r;
    asm("v_log_f32 %0, %1" : "=v"(r) : "v"(x));
    return r;
}

__device__ __forceinline__ float shup1(float x) {
#if __has_builtin(__builtin_amdgcn_mov_dpp)
    return __int_as_float(
        __builtin_amdgcn_mov_dpp(__float_as_int(x), 0x138, 0xF, 0xF, true));
#else
    return __shfl_up(x, 1);
#endif
}

// ---------------- conv + pool + relu + mask + row norms --------------------
// norms are pre-scaled by K_SCALE so the D2 matrix is born in the scaled
// base-2 domain.
__global__ __launch_bounds__(128) void conv_k(
    const float* __restrict__ x, const float* __restrict__ w,
    const float* __restrict__ cb, const float* __restrict__ mask,
    float* __restrict__ h, u16* __restrict__ hbf, float* __restrict__ norms)
{
    int b = blockIdx.x;
    int l0 = blockIdx.y * 8;
    int d = threadIdx.x;
    __shared__ float xs[12][36];
    __shared__ float red2[8][2];
    for (int v = d; v < 12 * 35; v += 128) {
        int c = v / 35, off = v % 35;
        int gi = 4 * l0 - 2 + off;
        xs[c][off] = (gi >= 0 && gi < 4095) ? x[((long)b * 12 + c) * 4095 + gi] : 0.f;
    }
    __syncthreads();
    float s[8];
#pragma unroll
    for (int l = 0; l < 8; ++l) s[l] = 0.f;
    for (int c = 0; c < 12; ++c) {
        const float* wp = w + (d * 12 + c) * 4;
        float w0 = wp[0], w1 = wp[1], w2 = wp[2], w3 = wp[3];
        float e0 = w0, e1 = w0 + w1, e2 = w0 + w1 + w2, e3 = w0 + w1 + w2 + w3;
        float e4 = w1 + w2 + w3, e5 = w2 + w3, e6 = w3;
#pragma unroll
        for (int l = 0; l < 8; ++l) {
            int ba = 4 * l;
            s[l] += xs[c][ba] * e0 + xs[c][ba + 1] * e1 + xs[c][ba + 2] * e2 +
                    xs[c][ba + 3] * e3 + xs[c][ba + 4] * e4 + xs[c][ba + 5] * e5 +
                    xs[c][ba + 6] * e6;
        }
    }
    float cbd = cb[d];
#pragma unroll
    for (int l = 0; l < 8; ++l) {
        int gl = l0 + l;
        float val = fmaxf(cbd + 0.25f * s[l], 0.f) * mask[b * L_SEQ + gl];
        long idx = ((long)(b * L_SEQ + gl)) * DM + d;
        h[idx] = val;
        hbf[idx] = f2b(val);
        float vsq = val * val;
#pragma unroll
        for (int m = 1; m < 64; m <<= 1) vsq += __shfl_xor(vsq, m);
        if ((d & 63) == 0) red2[l][d >> 6] = vsq;
    }
    __syncthreads();
    if (d < 8)
        norms[(long)b * L_SEQ + l0 + d] = (red2[d][0] + red2[d][1]) * K_SCALE;
}

// ----------------------- weight fp32 -> bf16 convert -----------------------
__global__ __launch_bounds__(256) void wcvt_k(
    const float* __restrict__ w1, const float* __restrict__ w2,
    const float* __restrict__ w3, const float* __restrict__ w4,
    u16* __restrict__ o)
{
    int i = blockIdx.x * 256 + threadIdx.x;   // grid 200 -> 51200
    float v;
    if (i < 16384) v = w1[i];
    else if (i < 32768) v = w2[i - 16384];
    else if (i < 49152) v = w3[i - 32768];
    else v = w4[i - 49152];
    o[i] = f2b(v);
}

// --------------------------- MFMA bf16 GEMMs -------------------------------
enum MGMode { G_D2, G_AV };

template <int MODE>
__global__ __launch_bounds__(256) void mgemm_k(
    const u16* __restrict__ A0, const u16* __restrict__ B0, void* __restrict__ C0,
    const float* __restrict__ e0, const float* __restrict__ rsum)
{
    constexpr int LDK = (MODE == G_AV) ? 1024 : 128;
    constexpr int KK = LDK / 32;
    const int z = blockIdx.z;
    const u16* A = A0 + (MODE == G_D2 ? 0L : (long)z * 1048576L);
    const u16* B = B0 + (long)z * 131072L;
    const int tid = threadIdx.x, wv = tid >> 6, lane = tid & 63;
    const int m0 = blockIdx.x * 64, n0 = blockIdx.y * 64;
    const int co = lane & 15;
    const int q8 = (lane >> 4) << 3;
    const int mrow = m0 + 16 * wv + co;

    f32x4 acc[4];
#pragma unroll
    for (int tn = 0; tn < 4; ++tn) acc[tn] = 0.f;

    for (int kk = 0; kk < KK; ++kk) {
        const int k0 = kk * 32 + q8;
        const s16x8 a = *reinterpret_cast<const s16x8*>(A + (long)mrow * LDK + k0);
#pragma unroll
        for (int tn = 0; tn < 4; ++tn) {
            const s16x8 b = *reinterpret_cast<const s16x8*>(
                B + (long)(n0 + 16 * tn + co) * LDK + k0);
            acc[tn] = __builtin_amdgcn_mfma_f32_16x16x32_bf16(a, b, acc[tn], 0, 0, 0);
        }
    }

    const int li0 = 16 * wv + ((lane >> 4) << 2);

    if (MODE == G_D2) {
        __shared__ float Cs[64][66];
        float ni[4];
#pragma unroll
        for (int r = 0; r < 4; ++r) ni[r] = e0[m0 + li0 + r];
#pragma unroll
        for (int tn = 0; tn < 4; ++tn) {
            float nj = e0[(long)z * L_SEQ + n0 + 16 * tn + co];
#pragma unroll
            for (int r = 0; r < 4; ++r)
                Cs[li0 + r][16 * tn + co] = ni[r] + nj - K2_SCALE * acc[tn][r];
        }
        __syncthreads();
        u16* Cu = (u16*)C0 + (long)z * 1048576L;
        for (int q = 0; q < 32; ++q) {
            int dd = wv * 32 + q;
            if (dd < 127) {
                int d = m0 + n0 + dd;
                int ilo = max(m0, d - n0 - 63);
                int ihi = min(m0 + 63, d - n0);
                int i = ilo + lane;
                if (i <= ihi)
                    Cu[(long)(((d & 1023) << 10) + i)] = f2b(Cs[i - m0][d - n0 - i]);
            }
        }
        return;
    }
    // G_AV: t0b (bf16) = (P . V) * rsuminv[row]
    {
        u16* Cb = (u16*)C0 + (long)z * 131072L;
        float rsv[4];
#pragma unroll
        for (int r = 0; r < 4; ++r) rsv[r] = rsum[(long)z * L_SEQ + m0 + li0 + r];
#pragma unroll
        for (int tn = 0; tn < 4; ++tn)
#pragma unroll
            for (int r = 0; r < 4; ++r)
                Cb[(long)(m0 + li0 + r) * 128 + n0 + 16 * tn + co] =
                    f2b(acc[tn][r] * rsv[r]);
    }
}

// ---------------------- SC (MFMA scores), one launch -----------------------
// reads R from Rm (dtw output), writes scores into So (the dead D region)
__global__ __launch_bounds__(256) void sc_k(
    const u16* __restrict__ qb, const u16* __restrict__ kb, u16* __restrict__ So,
    const float* __restrict__ mnmx, const float* __restrict__ mask,
    const u16* __restrict__ Rm)
{
    const int s = blockIdx.x;
    const int tid = threadIdx.x;
    __shared__ float Rs[64][66];

    const int z = s >> 8;
    const int m0 = (s & 15) * 64, n0 = ((s >> 4) & 15) * 64;
    const u16* A = qb + (long)z * 131072L;
    const u16* B = kb + (long)z * 131072L;
    const int wv = tid >> 6, lane = tid & 63;
    const int co = lane & 15;
    const int q8 = (lane >> 4) << 3;
    const int mrow = m0 + 16 * wv + co;

    f32x4 acc[4];
#pragma unroll
    for (int tn = 0; tn < 4; ++tn) acc[tn] = 0.f;
    for (int kk = 0; kk < 4; ++kk) {
        const int k0 = kk * 32 + q8;
        const s16x8 a = *reinterpret_cast<const s16x8*>(A + (long)mrow * 128 + k0);
#pragma unroll
        for (int tn = 0; tn < 4; ++tn) {
            const s16x8 b = *reinterpret_cast<const s16x8*>(
                B + (long)(n0 + 16 * tn + co) * 128 + k0);
            acc[tn] = __builtin_amdgcn_mfma_f32_16x16x32_bf16(a, b, acc[tn], 0, 0, 0);
        }
    }
    const int li0 = 16 * wv + ((lane >> 4) << 2);
    const u16* Rz = Rm + (long)z * 1048576L;
    for (int q = 0; q < 32; ++q) {
        int dd = wv * 32 + q;
        if (dd < 127) {
            int d = m0 + n0 + dd;
            int ilo = max(m0, d - n0 - 63);
            int ihi = min(m0 + 63, d - n0);
            int i = ilo + lane;
            if (i <= ihi)
                Rs[i - m0][d - n0 - i] = b2f(Rz[(long)(((d & 1023) << 10) + i)]);
        }
    }
    __syncthreads();
    float mn = fminf(mnmx[4 * z + 0], mnmx[4 * z + 2]);
    float mx = fmaxf(mnmx[4 * z + 1], mnmx[4 * z + 3]);
    float inv = 1.f / (mx - mn);
    u16* Cu = So + (long)z * 1048576L;
#pragma unroll
    for (int tn = 0; tn < 4; ++tn) {
        int gj = n0 + 16 * tn + co;
        float kp = (mask[(long)z * L_SEQ + gj] > 0.f) ? 0.f : -INF_F;
#pragma unroll
        for (int r = 0; r < 4; ++r) {
            float val = acc[tn][r] * 0.08838834764831845f +
                        (Rs[li0 + r][16 * tn + co] - mn) * inv + 1.f + kp;
            Cu[(long)(m0 + li0 + r) * 1024 + gj] = f2b(val);
        }
    }
}

// ----------------- MFMA weight GEMMs (M=32768, K=128) ----------------------
enum WMode { W2_WOUT, W2_FF1, W2_FF2, W2_LIN };

template <int MODE, int NT>
__global__ __launch_bounds__(256) void wgemm_k(
    const u16* __restrict__ A, const u16* __restrict__ Bw, void* __restrict__ Cv,
    const float* __restrict__ bias, const float* __restrict__ e1)
{
    const int tid = threadIdx.x, wv = tid >> 6, lane = tid & 63;
    const int m0 = blockIdx.x * 64, n0 = blockIdx.y * 64;
    const int co = lane & 15;
    const int q8 = (lane >> 4) << 3;
    const int mrow = m0 + 16 * wv + co;

    f32x4 acc[NT];
#pragma unroll
    for (int tn = 0; tn < NT; ++tn) acc[tn] = 0.f;
    for (int kk = 0; kk < 4; ++kk) {
        const int k0 = kk * 32 + q8;
        const s16x8 a = *reinterpret_cast<const s16x8*>(A + (long)mrow * 128 + k0);
#pragma unroll
        for (int tn = 0; tn < NT; ++tn) {
            const s16x8 b = *reinterpret_cast<const s16x8*>(
                Bw + (long)(n0 + 16 * tn + co) * 128 + k0);
            acc[tn] = __builtin_amdgcn_mfma_f32_16x16x32_bf16(a, b, acc[tn], 0, 0, 0);
        }
    }
    const int li0 = 16 * wv + ((lane >> 4) << 2);
#pragma unroll
    for (int tn = 0; tn < NT; ++tn) {
        int gj = n0 + 16 * tn + co;
#pragma unroll
        for (int r = 0; r < 4; ++r) {
            int gi = m0 + li0 + r;
            long idx = (long)gi * 128 + gj;
            float v = acc[tn][r];
            if (MODE == W2_WOUT) {
                ((float*)Cv)[idx] = v + bias[gj] + e1[idx];
            } else if (MODE == W2_FF1) {
                ((u16*)Cv)[idx] = f2b(fmaxf(v + bias[gj], 0.f));
            } else if (MODE == W2_FF2) {
                ((float*)Cv)[idx] = v + bias[gj] + e1[idx];
            } else if (MODE == W2_LIN) {
                ((float*)Cv)[(long)gi * 16 + gj] = v * e1[gi];
            }
        }
    }
}

// ------------------------------- soft-DTW ----------------------------------
// base-2 scaled domain: n = d + mn - log2(1 + 2^(mn-md) + 2^(mn-mx))
__device__ __forceinline__ float softmin3(float d, float rl, float ru, float rul)
{
    float mn = fminf(rul, fminf(ru, rl));
    float md = __builtin_amdgcn_fmed3f(rul, ru, rl);
    float mx = fmaxf(rul, fmaxf(ru, rl));
    float s = 1.f + fexp2(mn - md) + fexp2(mn - mx);
    return d + mn - flog2(s);
}

// D loads / R stores via inline asm: 8 loads in flight across the 8-step
// chain, counted s_waitcnt vmcnt(8) at group end (leaves this group's 8
// stores outstanding), never drains to 0 in the main loop.
template <bool EDGE>
__device__ __forceinline__ void dtw_chunk1(
    const u16* __restrict__ Dz, u16* __restrict__ Rz,
    const float* __restrict__ botp, float* __restrict__ botw,
    int W, int lane, bool lane0, int rowbase, int row, int T0,
    float& cur, float& upc, float& upp,
    float (&dbuf)[8], float (&bb)[9], unsigned (&dn)[8])
{
    u16* sp = Rz + (((T0 & 1023) << 10) + row);
    const bool w0 = (W == 0);
    const bool wstore = (W < 15);
    for (int g = 0; g < 4; ++g) {
        const int tg = T0 + (g << 3);
        // issue next group's 8 D loads (stay in flight across the steps)
#pragma unroll
        for (int s = 0; s < 8; ++s) {
            const u16* ap = Dz + ((((tg + 8 + s) & 1023) << 10) + row);
            asm volatile("global_load_ushort %0, %1, off"
                         : "=v"(dn[s]) : "v"(ap));
        }
        float bn[9];
        if (W > 0 && g < 3) {
            const int jn = tg + 7 - rowbase;
#pragma unroll
            for (int q = 0; q < 9; ++q) bn[q] = botp[(jn + q) & 511];
        }
#pragma unroll
        for (int s = 0; s < 8; ++s) {
            const int t = tg + s;
            const int j = t - row;
            float ru = lane0 ? (w0 ? INF_F : bb[s + 1]) : upc;
            float rul = upp;
            if (EDGE) {
                rul = lane0 ? (w0 ? ((j == 0) ? 0.f : INF_F)
                                  : ((j < 1) ? INF_F : upp))
                            : upp;
            } else {
                rul = (lane0 && w0) ? INF_F : rul;
            }
            float n = softmin3(dbuf[s], cur, ru, rul);
            if (EDGE) {
                bool v = ((unsigned)j < 1024u);
                n = v ? n : INF_F;
                if (v) {
                    unsigned bits = __float_as_uint(n) >> 16;
                    asm volatile("global_store_short %0, %1, off"
                                 :: "v"(sp), "v"(bits));
                }
                if (lane == 63 && v && wstore) botw[j & 511] = n;
            } else {
                unsigned bits = __float_as_uint(n) >> 16;
                asm volatile("global_store_short %0, %1, off"
                             :: "v"(sp), "v"(bits));
                if (lane == 63 && wstore) botw[j & 511] = n;
            }
            upp = ru;
            cur = n;
            upc = shup1(n);
            sp += 1024;
        }
        // retire the 8 loads (8 newest ops = this group's stores may remain)
        asm volatile("s_waitcnt vmcnt(8)");
        __builtin_amdgcn_sched_barrier(0);
#pragma unroll
        for (int s = 0; s < 8; ++s) dbuf[s] = __uint_as_float(dn[s] << 16);
        if (W > 0 && g < 3) {
#pragma unroll
            for (int q = 0; q < 9; ++q) bb[q] = bn[q];
        }
    }
}

// dtw (blocks 0..31: 1 per sample, 16 waves) + QKV backfill (blocks 32..799)
__global__ __launch_bounds__(1024, 4) void dtw_qkv_k(
    const u16* __restrict__ Dm, u16* __restrict__ Rm,
    const float* __restrict__ h, const float* __restrict__ w_in,
    const float* __restrict__ b_in, u16* __restrict__ qb, u16* __restrict__ vt)
{
    // unioned LDS: QKV As(16640)+Bs(16640) | QKV Tt(33280) | dtw bot(30720)
    __shared__ __align__(16) char smem[33280];

    if (blockIdx.x >= 32) {
        // ---- QKV backfill: four 64x64 tiles per 1024-thread block ----
        float (*As)[16][65] = reinterpret_cast<float (*)[16][65]>(smem);
        float (*Bs)[16][65] = reinterpret_cast<float (*)[16][65]>(smem + 16640);
        const int quarter = threadIdx.x >> 8;
        const int tid = threadIdx.x & 255;
        const int t = ((blockIdx.x - 32) << 2) + quarter;   // 0..3071
        const int m0 = (t & 511) << 6;
        const int n0 = (t >> 9) << 6;                       // block-uniform
        int tx = tid & 15, ty = tid >> 4;
        float acc[4][4] = {};
        int am = tid >> 2;
        int ak = (tid & 3) << 2;
        for (int kk = 0; kk < 128; kk += 16) {
            {
                const float4 av = *reinterpret_cast<const float4*>(
                    h + (long)(m0 + am) * 128 + kk + ak);
                As[quarter][ak + 0][am] = av.x;
                As[quarter][ak + 1][am] = av.y;
                As[quarter][ak + 2][am] = av.z;
                As[quarter][ak + 3][am] = av.w;
            }
            {
                const float4 bv = *reinterpret_cast<const float4*>(
                    w_in + (long)(n0 + am) * 128 + kk + ak);
                Bs[quarter][ak + 0][am] = bv.x;
                Bs[quarter][ak + 1][am] = bv.y;
                Bs[quarter][ak + 2][am] = bv.z;
                Bs[quarter][ak + 3][am] = bv.w;
            }
            __syncthreads();
#pragma unroll
            for (int kc = 0; kc < 16; ++kc) {
                float a0 = As[quarter][kc][ty * 4 + 0], a1 = As[quarter][kc][ty * 4 + 1];
                float a2 = As[quarter][kc][ty * 4 + 2], a3 = As[quarter][kc][ty * 4 + 3];
                float b0 = Bs[quarter][kc][tx * 4 + 0], b1 = Bs[quarter][kc][tx * 4 + 1];
                float b2 = Bs[quarter][kc][tx * 4 + 2], b3 = Bs[quarter][kc][tx * 4 + 3];
                acc[0][0] += a0 * b0; acc[0][1] += a0 * b1; acc[0][2] += a0 * b2; acc[0][3] += a0 * b3;
                acc[1][0] += a1 * b0; acc[1][1] += a1 * b1; acc[1][2] += a1 * b2; acc[1][3] += a1 * b3;
                acc[2][0] += a2 * b0; acc[2][1] += a2 * b1; acc[2][2] += a2 * b2; acc[2][3] += a2 * b3;
                acc[3][0] += a3 * b0; acc[3][1] += a3 * b1; acc[3][2] += a3 * b2; acc[3][3] += a3 * b3;
            }
            __syncthreads();
        }
        if (n0 >= 256) {
            // v-tile: write TRANSPOSED into vt [d,1024] via LDS (Tt aliases As/Bs;
            // safe: k-loop ends with a block-wide barrier)
            u16 (*Tt)[64][65] = reinterpret_cast<u16 (*)[64][65]>(smem);
#pragma unroll
            for (int i = 0; i < 4; ++i)
#pragma unroll
                for (int j = 0; j < 4; ++j)
                    Tt[quarter][tx * 4 + j][ty * 4 + i] =
                        f2b(acc[i][j] + b_in[n0 + tx * 4 + j]);
            __syncthreads();
            const int z = m0 >> 10;
            const int lbase = m0 & 1023;
            const int dbase = n0 - 256;
            u16* dst = vt + (long)z * 131072L;
#pragma unroll
            for (int i = 0; i < 16; ++i) {
                int idx = tid + 256 * i;
                int dj = idx >> 6, li = idx & 63;
                dst[(long)(dbase + dj) * 1024 + lbase + li] = Tt[quarter][dj][li];
            }
            return;
        }
        u16* Cu = qb + ((long)(n0 >> 7)) * 4194304L;
        int cb = (n0 & 127) + tx * 4;
#pragma unroll
        for (int i = 0; i < 4; ++i) {
            int gi = m0 + ty * 4 + i;
            ushort4 sv;
            u16* svp = &sv.x;
#pragma unroll
            for (int j = 0; j < 4; ++j)
                svp[j] = f2b(acc[i][j] + b_in[n0 + tx * 4 + j]);
            *reinterpret_cast<ushort4*>(Cu + (long)gi * 128 + cb) = sv;
        }
        return;
    }

    // ------------------------------- dtw ---------------------------------
    float (*bot)[512] = reinterpret_cast<float (*)[512]>(smem);
    const int z = blockIdx.x;
    const u16* Dz = Dm + (long)z * 1048576L;
    u16* Rz = Rm + (long)z * 1048576L;
    const int tid = threadIdx.x;
    const int W = tid >> 6;           // 0..15, 64 rows each
    const int lane = tid & 63;
    const bool lane0 = (lane == 0);
    const int rowbase = 64 * W;
    const int row = rowbase + lane;

    float* botw = (W < 15) ? bot[W] : bot[0];
    const float* botp = (W > 0) ? bot[W - 1] : bot[0];

    float cur = INF_F, upc = INF_F, upp = INF_F;
    float dbuf[8];
    float bb[9];
    unsigned dn[8];
#pragma unroll
    for (int q = 0; q < 9; ++q) bb[q] = 0.f;
#pragma unroll
    for (int q = 0; q < 8; ++q) dn[q] = 0;

    const int fc = 2 * W;
    for (int e = 0; e < 79; ++e) {
        const int c = e - W;
        const int o = c - fc;
        if (o >= 0 && o <= 33) {
            const int T0 = c << 5;
            if (o == 0) {   // prime D queue (8 steps)
#pragma unroll
                for (int s = 0; s < 8; ++s)
                    dbuf[s] = b2f(Dz[((((T0 + s) & 1023) << 10) + row)]);
            }
            if (W > 0) {    // bot columns for the chunk's first group
                const int jb = T0 - rowbase - 1;
#pragma unroll
                for (int q = 0; q < 9; ++q) bb[q] = botp[(jb + q) & 511];
            }
            if (o < 2 || o >= 32)
                dtw_chunk1<true>(Dz, Rz, botp, botw, W, lane, lane0,
                                 rowbase, row, T0, cur, upc, upp, dbuf, bb, dn);
            else
                dtw_chunk1<false>(Dz, Rz, botp, botw, W, lane, lane0,
                                  rowbase, row, T0, cur, upc, upp, dbuf, bb, dn);
        }
        __syncthreads();
    }
}

// ------------------- min/max over Rmat (one block per sample) --------------
// every Rmat slot holds exactly one valid R value, so a linear scan gives
// the matrix min/max.
__global__ __launch_bounds__(1024) void mm_k(const u16* __restrict__ Rm,
                                             float* __restrict__ mnmx)
{
    const int z = blockIdx.x;
    const uint4* p = reinterpret_cast<const uint4*>(Rm + (long)z * 1048576L);
    const int tid = threadIdx.x;
    float mn = INF_F, mx = -INF_F;
    for (int it = 0; it < 128; ++it) {
        uint4 v = p[it * 1024 + tid];
        unsigned wv[4] = {v.x, v.y, v.z, v.w};
#pragma unroll
        for (int q = 0; q < 4; ++q) {
            float lo = __uint_as_float(wv[q] << 16);
            float hi = __uint_as_float(wv[q] & 0xFFFF0000u);
            mn = fminf(mn, fminf(lo, hi));
            mx = fmaxf(mx, fmaxf(lo, hi));
        }
    }
    __shared__ float rmn[1024];
    __shared__ float rmx[1024];
    rmn[tid] = mn;
    rmx[tid] = mx;
    __syncthreads();
    for (int s2 = 512; s2 > 0; s2 >>= 1) {
        if (tid < s2) {
            rmn[tid] = fminf(rmn[tid], rmn[tid + s2]);
            rmx[tid] = fmaxf(rmx[tid], rmx[tid + s2]);
        }
        __syncthreads();
    }
    if (tid == 0) {
        mnmx[z * 4 + 0] = rmn[0];
        mnmx[z * 4 + 1] = rmx[0];
        mnmx[z * 4 + 2] = rmn[0];
        mnmx[z * 4 + 3] = rmx[0];
    }
}

// ---------- softmax row stats + in-place P = exp(s-max), wave/row ----------
__global__ __launch_bounds__(256) void smax_k(u16* __restrict__ S,
                                              float* __restrict__ rsuminv)
{
    long row = (long)blockIdx.x * 4 + (threadIdx.x >> 6);
    int lane = threadIdx.x & 63;
    u16* p = S + row * L_SEQ + lane * 16;
    ushort4 v[4];
#pragma unroll
    for (int q = 0; q < 4; ++q) v[q] = reinterpret_cast<ushort4*>(p)[q];
    float f[16];
#pragma unroll
    for (int q = 0; q < 4; ++q) {
        f[4 * q + 0] = b2f(v[q].x);
        f[4 * q + 1] = b2f(v[q].y);
        f[4 * q + 2] = b2f(v[q].z);
        f[4 * q + 3] = b2f(v[q].w);
    }
    float m = f[0];
#pragma unroll
    for (int i = 1; i < 16; ++i) m = fmaxf(m, f[i]);
#pragma unroll
    for (int d2 = 1; d2 < 64; d2 <<= 1) m = fmaxf(m, __shfl_xor(m, d2));
    float s = 0.f;
#pragma unroll
    for (int i = 0; i < 16; ++i) {
        f[i] = __expf(f[i] - m);
        s += f[i];
    }
#pragma unroll
    for (int q = 0; q < 4; ++q) {
        ushort4 pv;
        pv.x = f2b(f[4 * q + 0]);
        pv.y = f2b(f[4 * q + 1]);
        pv.z = f2b(f[4 * q + 2]);
        pv.w = f2b(f[4 * q + 3]);
        reinterpret_cast<ushort4*>(p)[q] = pv;
    }
#pragma unroll
    for (int d2 = 1; d2 < 64; d2 <<= 1) s += __shfl_xor(s, d2);
    if (lane == 0) rsuminv[row] = 1.f / s;
}

// ------------------ layernorm (wave/row), fp32 + bf16 out ------------------
__global__ __launch_bounds__(256) void ln_k(float* __restrict__ X,
                                            u16* __restrict__ Xb,
                                            const float* __restrict__ g,
                                            const float* __restrict__ b)
{
    long row = (long)blockIdx.x * 4 + (threadIdx.x >> 6);
    int lane = threadIdx.x & 63;
    float2 x = *reinterpret_cast<float2*>(X + row * DM + lane * 2);
    float s = x.x + x.y;
    float q = x.x * x.x + x.y * x.y;
#pragma unroll
    for (int m = 1; m < 64; m <<= 1) {
        s += __shfl_xor(s, m);
        q += __shfl_xor(q, m);
    }
    float mean = s * (1.f / 128.f);
    float var = q * (1.f / 128.f) - mean * mean;
    float rstd = rsqrtf(var + 1e-5f);
    float2 o;
    o.x = (x.x - mean) * rstd * g[lane * 2 + 0] + b[lane * 2 + 0];
    o.y = (x.y - mean) * rstd * g[lane * 2 + 1] + b[lane * 2 + 1];
    *reinterpret_cast<float2*>(X + row * DM + lane * 2) = o;
    ushort2 ob;
    ob.x = f2b(o.x);
    ob.y = f2b(o.y);
    *reinterpret_cast<ushort2*>(Xb + row * DM + lane * 2) = ob;
}

// -------------------------------- lengths ----------------------------------
__global__ __launch_bounds__(256) void len_k(const float* __restrict__ mask,
                                             float* __restrict__ out)
{
    int b = blockIdx.x;
    int t = threadIdx.x;
    const float4 v = reinterpret_cast<const float4*>(mask + b * L_SEQ)[t];
    __shared__ float red[256];
    red[t] = v.x + v.y + v.z + v.w;
    __syncthreads();
    for (int s = 128; s > 0; s >>= 1) {
        if (t < s) red[t] += red[t + s];
        __syncthreads();
    }
    if (t == 0) out[b] = red[0];
}

// ------------------------------- launcher ----------------------------------
extern "C" void kernel_launch(void* const* d_in, const int* in_sizes, int n_in,
                              void* d_out, int out_size, void* d_ws, size_t ws_size,
                              hipStream_t stream)
{
    const float* x      = (const float*)d_in[0];
    const float* mask   = (const float*)d_in[1];
    const float* conv_w = (const float*)d_in[2];
    const float* conv_b = (const float*)d_in[3];
    const float* w_in   = (const float*)d_in[4];
    const float* b_in   = (const float*)d_in[5];
    const float* w_out  = (const float*)d_in[6];
    const float* b_out  = (const float*)d_in[7];
    const float* w_ff1  = (const float*)d_in[8];
    const float* b_ff1  = (const float*)d_in[9];
    const float* w_ff2  = (const float*)d_in[10];
    const float* b_ff2  = (const float*)d_in[11];
    const float* ln1_g  = (const float*)d_in[12];
    const float* ln1_b  = (const float*)d_in[13];
    const float* ln2_g  = (const float*)d_in[14];
    const float* ln2_b  = (const float*)d_in[15];
    const float* w_lin  = (const float*)d_in[16];
    float* out = (float*)d_out;

    float* ws    = (float*)d_ws;
    float* h     = ws;
    u16*   qb    = (u16*)(ws + 4194304L);
    u16*   kb    = qb + 4194304L;
    u16*   t0b   = qb + 8388608L;
    u16*   vt    = qb + 12582912L;
    float* t0    = ws + 16777216L;
    float* t1    = ws + 20971520L;
    u16*   t1b   = (u16*)(ws + 25165824L);    // overlaps hbf (dead after D2)
    u16*   hbf   = (u16*)(ws + 25165824L);
    u16*   t2b   = t1b + 4194304L;            // overlaps dead mnmx region
    float* mnmx  = ws + 27297792L;
    float* norms = ws + 29360128L;
    u16*   woutb = (u16*)norms;               // weights after D2 consumed norms
    u16*   wff1b = woutb + 16384;
    u16*   wff2b = woutb + 32768;
    u16*   wlinb = woutb + 49152;
    float* rsum  = ws + 29425664L;
    u16*   Dmat  = (u16*)(ws + 29458496L);    // D (dtw input), then P after sc
    u16*   Rmat  = (u16*)(ws + 46235712L);    // R (dtw output, mm/sc input)
    u16*   Pmat  = Dmat;                      // scores/P (D dead after dtw)

    conv_k<<<dim3(32, 128), 128, 0, stream>>>(x, conv_w, conv_b, mask, h, hbf, norms);
    mgemm_k<G_D2><<<dim3(16, 16, 32), 256, 0, stream>>>(
        hbf, hbf, Dmat, norms, nullptr);
    wcvt_k<<<200, 256, 0, stream>>>(w_out, w_ff1, w_ff2, w_lin, woutb);
    // dtw (32 blocks, 1/sample, 16 waves) + qkv backfill (768 blocks x 4 tiles)
    dtw_qkv_k<<<800, 1024, 0, stream>>>(Dmat, Rmat, h, w_in, b_in, qb, vt);
    mm_k<<<32, 1024, 0, stream>>>(Rmat, mnmx);
    sc_k<<<8192, 256, 0, stream>>>(qb, kb, Pmat, mnmx, mask, Rmat);
    smax_k<<<8192, 256, 0, stream>>>(Pmat, rsum);
    mgemm_k<G_AV><<<dim3(16, 2, 32), 256, 0, stream>>>(
        Pmat, vt, t0b, nullptr, rsum);
    wgemm_k<W2_WOUT, 4><<<dim3(512, 2), 256, 0, stream>>>(
        t0b, woutb, t1, b_out, h);
    ln_k<<<8192, 256, 0, stream>>>(t1, t1b, ln1_g, ln1_b);
    wgemm_k<W2_FF1, 4><<<dim3(512, 2), 256, 0, stream>>>(
        t1b, wff1b, t2b, b_ff1, nullptr);
    wgemm_k<W2_FF2, 4><<<dim3(512, 2), 256, 0, stream>>>(
        t2b, wff2b, t0, b_ff2, t1);
    ln_k<<<8192, 256, 0, stream>>>(t0, t0b, ln2_g, ln2_b);
    wgemm_k<W2_LIN, 1><<<dim3(512, 1), 256, 0, stream>>>(
        t0b, wlinb, out, nullptr, mask);
    len_k<<<32, 256, 0, stream>>>(mask, out + 32768L * 16);
}